// Round 18
// baseline (565.453 us; speedup 1.0000x reference)
//
#include <hip/hip_runtime.h>
#include <hip/hip_bf16.h>
#include <stdint.h>

// STGCN block, MI355X gfx950. B=8 N=512 C=H=O=64 L=256 K=3.
// ALL global I/O is float32 (reference dtypes). Internal intermediates bf16.
// ALGEBRAIC RESTRUCTURE: conv(l) commutes with adj-GEMM(n):
//   pre = conv2(adj@xw+gb)+b2+br+res = adj @ conv2_zp(xw) + bias(l) + res
// where bias(l)[o] = b2+br+ Σ_{valid taps} s[tap][o], s[tap][o]=Σ_d W2[o,d,tap]*gb[d].
// LAYOUTS: y (=conv2_zp(conv1)) / core (=adj@y+bias) : [bn][l][d];
// res : [bn][v][t] chunk-major; pre : [bn][o][l] CANONICAL.
// P4 is pure streaming, NO LDS bounce: iterate chunk-major; core via u16x4
// (32B-sector pattern); pre written with direct scalar u16 stores that are
// sector-perfect (o<-lq gives 4 groups, l<-lr gives contiguous 32B runs).
// Pipeline:
//   P0 prep: W1G premix (conv1*gw), b1g, w2t, wrt, bias3[3][64]
//   P1: res = wr@x ; t1 = conv1(x;W1G)+b1g ; y = conv2_zp(t1) -> bufA [l][d]
//   P3: core[b] = adj[b] @ y[b] + bias(l) -> d_out 1st half [l][d]
//   P4: STREAM pre = core + res -> bufA [o][l] + BN partials [128][4096]
//   P5: reduce partials -> mean, rstd
//   P6: out = relu((pre-mean)*rstd*gamma+beta) -> d_out (f32)
// MFMA (m91/m97): A row=lane&15,k=(lane>>4)*8+e; B col=lane&15; D col=lane&15,row=(lane>>4)*4+reg
// LDS tile rows: 128B of 64 bf16, byte swizzle cb ^= ((row&7)<<4).

typedef unsigned short u16;
typedef unsigned int   u32;
typedef __attribute__((ext_vector_type(8))) short           bf16x8;
typedef __attribute__((ext_vector_type(8))) unsigned short  u16x8;
typedef __attribute__((ext_vector_type(4))) unsigned short  u16x4;
typedef __attribute__((ext_vector_type(4))) float           f32x4;

__device__ __forceinline__ float bf2f(u16 v){
  union { u32 u; float f; } x; x.u = ((u32)v) << 16; return x.f;
}
__device__ __forceinline__ u16 f2bf(float f){
  __hip_bfloat16 h = __float2bfloat16(f);
  return *reinterpret_cast<u16*>(&h);
}
__device__ __forceinline__ u32 swz(int row, int cbyte){
  return (u32)(row * 128) + (u32)(cbyte ^ ((row & 7) << 4));
}

// ---------------- P0: weight prep ----------------
__global__ __launch_bounds__(256) void k_prep(const float* __restrict__ w1, const float* __restrict__ b1,
    const float* __restrict__ gw, const float* __restrict__ w2, const float* __restrict__ wr,
    const float* __restrict__ gb, const float* __restrict__ b2, const float* __restrict__ br,
    u16* __restrict__ w1g, float* __restrict__ b1g, u16* __restrict__ w2t, u16* __restrict__ wrt,
    float* __restrict__ bias3){
  const int gt = blockIdx.x * 256 + threadIdx.x, gs = gridDim.x * 256;
  for (int e = gt; e < 12288; e += gs){
    int tap = e >> 12, rem = e & 4095, o = rem >> 6, c = rem & 63;
    w2t[e] = f2bf(w2[(o * 64 + c) * 3 + tap]);
    float s = 0.f;
    for (int h = 0; h < 64; ++h)
      s += gw[h * 64 + o] * w1[(h * 64 + c) * 3 + tap];   // o plays role of d
    w1g[e] = f2bf(s);
  }
  for (int e = gt; e < 4096; e += gs) wrt[e] = f2bf(wr[e]);
  for (int d = gt; d < 64; d += gs){
    float s = 0.f;
    for (int h = 0; h < 64; ++h) s += b1[h] * gw[h * 64 + d];
    b1g[d] = s;
  }
  for (int o = gt; o < 64; o += gs){
    float s0 = 0.f, s1 = 0.f, s2 = 0.f;
    for (int d = 0; d < 64; ++d){
      float g_ = gb[d];
      s0 += w2[(o * 64 + d) * 3 + 0] * g_;
      s1 += w2[(o * 64 + d) * 3 + 1] * g_;
      s2 += w2[(o * 64 + d) * 3 + 2] * g_;
    }
    float bb = b2[o] + br[o];
    bias3[o]       = bb + s1 + s2;        // l == 0   (tap0 invalid)
    bias3[64 + o]  = bb + s0 + s1 + s2;   // interior
    bias3[128 + o] = bb + s0 + s1;        // l == 255 (tap2 invalid)
  }
}

// ---------------- P1: res = wr@x ; t1 = conv1+b1g ; y = conv2_zp(t1) ----------------
__global__ __launch_bounds__(256) void k_p1(const float* __restrict__ x,
    const u16* __restrict__ w1g, const float* __restrict__ b1g,
    const u16* __restrict__ wrt, const u16* __restrict__ w2t,
    u16* __restrict__ outA, u16* __restrict__ outR){
  __shared__ u16 tile[16384];  // x_t [l][c] -> t1 [l][d] -> y [l][d]
  const int t = threadIdx.x;
  const size_t bn = (size_t)blockIdx.x + (size_t)blockIdx.y * 512;
  const float* xb = x + bn * 16384;

  // coalesced transpose-stage: each f32x4 load instr covers 16 fully-consumed lines.
  {
    const int c0 = (t >> 3) * 2;           // channel pair
    #pragma unroll
    for (int v = 0; v < 8; ++v){
      const int l0 = (t & 7) * 4 + v * 32;
      f32x4 a = *(const f32x4*)(xb + (size_t)c0 * 256 + l0);
      f32x4 b = *(const f32x4*)(xb + (size_t)(c0 + 1) * 256 + l0);
      #pragma unroll
      for (int e = 0; e < 4; ++e){
        u32 p = (u32)f2bf(a[e]) | ((u32)f2bf(b[e]) << 16);
        *(u32*)((char*)tile + swz(l0 + e, c0 * 2)) = p;
      }
    }
  }
  __syncthreads();
  const int w = t >> 6, ln = t & 63, lq = ln >> 4, lr = ln & 15;
  const bf16x8 z8 = {};

  // ---- residual: racc = wr @ x  (chunk-major contiguous store) ----
  {
    f32x4 racc[4][4];
    #pragma unroll
    for (int i = 0; i < 4; ++i)
      #pragma unroll
      for (int j = 0; j < 4; ++j) racc[i][j] = (f32x4){0.f, 0.f, 0.f, 0.f};
    #pragma unroll
    for (int kk = 0; kk < 2; ++kk){
      bf16x8 A[4];
      #pragma unroll
      for (int fo = 0; fo < 4; ++fo)
        A[fo] = *(const bf16x8*)(wrt + (fo * 16 + lr) * 64 + kk * 32 + lq * 8);
      #pragma unroll
      for (int fc = 0; fc < 4; ++fc){
        int l = w * 64 + fc * 16 + lr;
        bf16x8 B = *(const bf16x8*)((char*)tile + swz(l, kk * 64 + lq * 16));
        #pragma unroll
        for (int fo = 0; fo < 4; ++fo)
          racc[fo][fc] = __builtin_amdgcn_mfma_f32_16x16x32_bf16(A[fo], B, racc[fo][fc], 0, 0, 0);
      }
    }
    #pragma unroll
    for (int v = 0; v < 8; ++v){
      u16x8 ov;
      const int fo = v >> 1;
      #pragma unroll
      for (int h = 0; h < 2; ++h){
        const int fc = (v & 1) * 2 + h;
        #pragma unroll
        for (int r2 = 0; r2 < 4; ++r2)
          ov[h * 4 + r2] = f2bf(racc[fo][fc][r2]);
      }
      *(u16x8*)(outR + bn * 16384 + v * 2048 + t * 8) = ov;  // contiguous 2KB/instr
    }
  }

  // ---- t1 = conv1(x; W1G) (zero-pad) ----
  f32x4 acc[4][4];
  #pragma unroll
  for (int i = 0; i < 4; ++i)
    #pragma unroll
    for (int j = 0; j < 4; ++j) acc[i][j] = (f32x4){0.f, 0.f, 0.f, 0.f};
  #pragma unroll
  for (int tap = 0; tap < 3; ++tap){
    #pragma unroll
    for (int kk = 0; kk < 2; ++kk){
      bf16x8 A[4];
      #pragma unroll
      for (int fo = 0; fo < 4; ++fo)
        A[fo] = *(const bf16x8*)(w1g + tap * 4096 + (fo * 16 + lr) * 64 + kk * 32 + lq * 8);
      #pragma unroll
      for (int fc = 0; fc < 4; ++fc){
        int r = w * 64 + fc * 16 + lr + tap - 1;
        int rc = r < 0 ? 0 : (r > 255 ? 255 : r);
        bf16x8 B = *(const bf16x8*)((char*)tile + swz(rc, kk * 64 + lq * 16));
        if (r != rc) B = z8;
        #pragma unroll
        for (int fo = 0; fo < 4; ++fo)
          acc[fo][fc] = __builtin_amdgcn_mfma_f32_16x16x32_bf16(A[fo], B, acc[fo][fc], 0, 0, 0);
      }
    }
  }
  __syncthreads();   // all x reads done -> reuse tile as t1 [l][d]
  #pragma unroll
  for (int fo = 0; fo < 4; ++fo){
    float bb[4];
    #pragma unroll
    for (int r2 = 0; r2 < 4; ++r2) bb[r2] = b1g[fo * 16 + lq * 4 + r2];
    #pragma unroll
    for (int fc = 0; fc < 4; ++fc){
      int l = w * 64 + fc * 16 + lr;
      #pragma unroll
      for (int r2 = 0; r2 < 4; ++r2){
        int d = fo * 16 + lq * 4 + r2;
        *(u16*)((char*)tile + l * 128 + ((2 * d) ^ ((l & 7) << 4))) = f2bf(acc[fo][fc][r2] + bb[r2]);
      }
    }
  }
  __syncthreads();

  // ---- y = conv2_zeropad(t1; w2t) ----
  f32x4 acc2[4][4];
  #pragma unroll
  for (int i = 0; i < 4; ++i)
    #pragma unroll
    for (int j = 0; j < 4; ++j) acc2[i][j] = (f32x4){0.f, 0.f, 0.f, 0.f};
  #pragma unroll
  for (int tap = 0; tap < 3; ++tap){
    #pragma unroll
    for (int kk = 0; kk < 2; ++kk){
      bf16x8 A[4];
      #pragma unroll
      for (int fo = 0; fo < 4; ++fo)
        A[fo] = *(const bf16x8*)(w2t + tap * 4096 + (fo * 16 + lr) * 64 + kk * 32 + lq * 8);
      #pragma unroll
      for (int fc = 0; fc < 4; ++fc){
        int r = w * 64 + fc * 16 + lr + tap - 1;
        int rc = r < 0 ? 0 : (r > 255 ? 255 : r);
        bf16x8 B = *(const bf16x8*)((char*)tile + swz(rc, kk * 64 + lq * 16));
        if (r != rc) B = z8;
        #pragma unroll
        for (int fo = 0; fo < 4; ++fo)
          acc2[fo][fc] = __builtin_amdgcn_mfma_f32_16x16x32_bf16(A[fo], B, acc2[fo][fc], 0, 0, 0);
      }
    }
  }
  __syncthreads();   // all t1 reads done -> reuse tile as y [l][d]
  #pragma unroll
  for (int fo = 0; fo < 4; ++fo)
    #pragma unroll
    for (int fc = 0; fc < 4; ++fc){
      int l = w * 64 + fc * 16 + lr;
      #pragma unroll
      for (int r2 = 0; r2 < 4; ++r2){
        int d = fo * 16 + lq * 4 + r2;
        *(u16*)((char*)tile + l * 128 + ((2 * d) ^ ((l & 7) << 4))) = f2bf(acc2[fo][fc][r2]);
      }
    }
  __syncthreads();
  // vector store y [l][d]: 8 x u16x8, fully-lined
  u16* op = outA + bn * 16384;
  #pragma unroll
  for (int v = 0; v < 8; ++v){
    int flat = v * 2048 + t * 8;
    int l = flat >> 6, d0 = flat & 63;
    u16x8 val = *(const u16x8*)((char*)tile + l * 128 + ((d0 * 2) ^ ((l & 7) << 4)));
    *(u16x8*)(op + flat) = val;
  }
}

// ---------------- P3: core = adj @ y + bias(l)  (reg-prefetch, XCD swizzle) ----------------
__global__ __launch_bounds__(256) void k_p3(const u16* __restrict__ y,
    const float* __restrict__ adj, const float* __restrict__ bias3, u16* __restrict__ outB){
  __shared__ u16 At[8192];
  __shared__ u16 Bt[8192];
  const int t = threadIdx.x;
  const int wg = ((blockIdx.x & 7) << 9) | ((int)blockIdx.x >> 3);
  const int jt = wg & 127, nt = (wg >> 7) & 3, b = wg >> 9;
  const float* adjb = adj + ((size_t)b * 512 + (size_t)nt * 128) * 512;
  const u16* Xb = y + (size_t)b * 8388608 + (size_t)jt * 128;
  const int w = t >> 6, ln = t & 63, lq = ln >> 4, lr = ln & 15;
  const int wrow = w >> 1, wcol = w & 1;
  const int mpair = t & 31, jq = t >> 5;
  f32x4 acc[4][4];
  #pragma unroll
  for (int i = 0; i < 4; ++i)
    #pragma unroll
    for (int j = 0; j < 4; ++j) acc[i][j] = (f32x4){0.f, 0.f, 0.f, 0.f};

  f32x4 ra[8];
  u16x8 rb[4];
  auto LOADK = [&](int ks){
    #pragma unroll
    for (int it = 0; it < 8; ++it){
      int c = it * 256 + t;
      int row = c >> 4, mc = c & 15;
      ra[it] = *(const f32x4*)(adjb + (size_t)row * 512 + ks * 64 + mc * 4);
    }
    const u16* s0 = Xb + (size_t)(ks * 64 + mpair * 2) * 16384 + jq * 16;
    const u16* s1 = s0 + 16384;
    #pragma unroll
    for (int v2 = 0; v2 < 2; ++v2){
      rb[v2 * 2]     = *(const u16x8*)(s0 + v2 * 8);
      rb[v2 * 2 + 1] = *(const u16x8*)(s1 + v2 * 8);
    }
  };

  LOADK(0);
  for (int ks = 0; ks < 8; ++ks){
    #pragma unroll
    for (int it = 0; it < 8; ++it){
      int c = it * 256 + t;
      int row = c >> 4, mc = c & 15;
      u16x4 pk;
      #pragma unroll
      for (int e = 0; e < 4; ++e) pk[e] = f2bf(ra[it][e]);
      *(u16x4*)((char*)At + (u32)(row * 128) + (u32)((mc * 8) ^ ((row & 7) << 4))) = pk;
    }
    #pragma unroll
    for (int v2 = 0; v2 < 2; ++v2){
      #pragma unroll
      for (int e = 0; e < 8; ++e){
        u32 p = (u32)(u16)rb[v2 * 2][e] | ((u32)(u16)rb[v2 * 2 + 1][e] << 16);
        *(u32*)((char*)Bt + swz(jq * 16 + v2 * 8 + e, mpair * 4)) = p;
      }
    }
    __syncthreads();
    if (ks < 7) LOADK(ks + 1);
    #pragma unroll
    for (int kk = 0; kk < 2; ++kk){
      bf16x8 Af[4], Bf[4];
      #pragma unroll
      for (int f = 0; f < 4; ++f){
        int rA = wrow * 64 + f * 16 + lr;
        Af[f] = *(const bf16x8*)((char*)At + swz(rA, kk * 64 + lq * 16));
        int rB = wcol * 64 + f * 16 + lr;
        Bf[f] = *(const bf16x8*)((char*)Bt + swz(rB, kk * 64 + lq * 16));
      }
      #pragma unroll
      for (int fr = 0; fr < 4; ++fr)
        #pragma unroll
        for (int fc = 0; fc < 4; ++fc)
          acc[fr][fc] = __builtin_amdgcn_mfma_f32_16x16x32_bf16(Af[fr], Bf[fc], acc[fr][fc], 0, 0, 0);
    }
    __syncthreads();
  }
  const int l = jt * 2 + wcol;
  const float* bt = bias3 + ((l == 0) ? 0 : (l == 255 ? 128 : 64));
  float gbl[4];
  #pragma unroll
  for (int fc = 0; fc < 4; ++fc) gbl[fc] = bt[fc * 16 + lr];
  u16* ob = outB + ((size_t)b * 512 + (size_t)nt * 128) * 16384 + (size_t)jt * 128;
  #pragma unroll
  for (int fr = 0; fr < 4; ++fr)
    #pragma unroll
    for (int fc = 0; fc < 4; ++fc)
      #pragma unroll
      for (int r2 = 0; r2 < 4; ++r2){
        int n_ = wrow * 64 + fr * 16 + lq * 4 + r2;
        int j_ = wcol * 64 + fc * 16 + lr;
        ob[(size_t)n_ * 16384 + j_] = f2bf(acc[fr][fc][r2] + gbl[fc]);
      }
}

// ---------------- P4: STREAM pre = core + res ; BN partials (no LDS bounce) ----------------
__global__ __launch_bounds__(256) void k_p4(const u16* __restrict__ core,
    const u16* __restrict__ resv, u16* __restrict__ outP, float* __restrict__ spart){
  __shared__ float sc2[512];
  const int t = threadIdx.x;
  const size_t bn = (size_t)blockIdx.x;
  const int w = t >> 6, ln = t & 63, lq = ln >> 4, lr = ln & 15;
  const u16* cb = core + bn * 16384;   // [l][d]
  const u16* rb = resv + bn * 16384;   // chunk-major
  u16* op = outP + bn * 16384;         // canonical [o][l]
  float psum[16], psq[16];
  #pragma unroll
  for (int i = 0; i < 16; ++i){ psum[i] = 0.f; psq[i] = 0.f; }

  #pragma unroll
  for (int v = 0; v < 8; ++v){
    const int fo = v >> 1;
    u16x8 rv = *(const u16x8*)(rb + v * 2048 + t * 8);           // contiguous 2KB/instr
    #pragma unroll
    for (int h = 0; h < 2; ++h){
      const int fc = (v & 1) * 2 + h;
      const int l = w * 64 + fc * 16 + lr;
      u16x4 cv = *(const u16x4*)(cb + (size_t)l * 64 + fo * 16 + lq * 4);  // 32B-sector pattern
      #pragma unroll
      for (int r2 = 0; r2 < 4; ++r2){
        const int o = fo * 16 + lq * 4 + r2;
        float val = bf2f((u16)cv[r2]) + bf2f((u16)rv[h * 4 + r2]);
        op[o * 256 + l] = f2bf(val);   // sector-perfect: lq->4 groups, lr->32B runs
        psum[fo * 4 + r2] += val;
        psq[fo * 4 + r2]  += val * val;
      }
    }
  }

  // reduce over the 16 lr lanes, deterministic (r14-proven tail)
  #pragma unroll
  for (int i = 0; i < 16; ++i){
    #pragma unroll
    for (int m = 1; m < 16; m <<= 1){
      psum[i] += __shfl_xor(psum[i], m, 64);
      psq[i]  += __shfl_xor(psq[i],  m, 64);
    }
  }
  if (lr == 0){
    #pragma unroll
    for (int i = 0; i < 16; ++i){
      int o = (i >> 2) * 16 + lq * 4 + (i & 3);
      sc2[w * 128 + o]      = psum[i];
      sc2[w * 128 + 64 + o] = psq[i];
    }
  }
  __syncthreads();
  if (t < 128){
    float tot = sc2[t] + sc2[128 + t] + sc2[256 + t] + sc2[384 + t];
    spart[(size_t)t * 4096 + bn] = tot;   // [0..63]=sum(o), [64..127]=sumsq(o)
  }
}

// ---------------- P5: BN stats finalize ----------------
__global__ __launch_bounds__(256) void k_p5(const float* __restrict__ part, float* __restrict__ fin){
  const int o = blockIdx.x, t = threadIdx.x;
  float s1 = 0.f, s2 = 0.f;
  for (int k = t; k < 4096; k += 256){
    s1 += part[(size_t)o * 4096 + k];
    s2 += part[(size_t)(64 + o) * 4096 + k];
  }
  #pragma unroll
  for (int m = 32; m; m >>= 1){
    s1 += __shfl_down(s1, m, 64);
    s2 += __shfl_down(s2, m, 64);
  }
  __shared__ float red[8];
  if ((t & 63) == 0){ red[(t >> 6) * 2] = s1; red[(t >> 6) * 2 + 1] = s2; }
  __syncthreads();
  if (t == 0){
    float S1 = red[0] + red[2] + red[4] + red[6];
    float S2 = red[1] + red[3] + red[5] + red[7];
    const float invN = 1.f / 1048576.f;
    float mean = S1 * invN;
    float var = S2 * invN - mean * mean;
    fin[o] = mean;
    fin[64 + o] = rsqrtf(var + 1e-5f);
  }
}

// ---------------- P6: normalize + affine + relu (canonical [o][l] pre -> f32 out) ----------------
__global__ __launch_bounds__(256) void k_p6(const u16* __restrict__ pre, const float* __restrict__ fin,
    const float* __restrict__ gamma, const float* __restrict__ beta, float* __restrict__ out){
  __shared__ float ssca[64], soff[64];
  const int tt = threadIdx.x;
  if (tt < 64){
    float sc = fin[64 + tt] * gamma[tt];
    ssca[tt] = sc;
    soff[tt] = beta[tt] - fin[tt] * sc;
  }
  __syncthreads();
  const size_t nchunk = 8388608;  // 67108864 / 8
  for (size_t i = (size_t)blockIdx.x * 256 + tt; i < nchunk; i += (size_t)gridDim.x * 256){
    int o = (int)((i >> 5) & 63);
    float sca = ssca[o], off = soff[o];
    u16x8 v = *(const u16x8*)(pre + i * 8);
    f32x4 oa, ob;
    #pragma unroll
    for (int e = 0; e < 4; ++e){
      float f0 = bf2f(v[e]) * sca + off;
      float f1 = bf2f(v[4 + e]) * sca + off;
      oa[e] = f0 > 0.f ? f0 : 0.f;
      ob[e] = f1 > 0.f ? f1 : 0.f;
    }
    *(f32x4*)(out + i * 8)     = oa;
    *(f32x4*)(out + i * 8 + 4) = ob;
  }
}

extern "C" void kernel_launch(void* const* d_in, const int* in_sizes, int n_in,
                              void* d_out, int out_size, void* d_ws, size_t ws_size,
                              hipStream_t stream){
  const float* x     = (const float*)d_in[0];
  const float* adj   = (const float*)d_in[1];
  const float* w1    = (const float*)d_in[2];
  const float* b1    = (const float*)d_in[3];
  const float* gw    = (const float*)d_in[4];
  const float* gb    = (const float*)d_in[5];
  const float* w2    = (const float*)d_in[6];
  const float* b2    = (const float*)d_in[7];
  const float* wr    = (const float*)d_in[8];
  const float* br    = (const float*)d_in[9];
  const float* gamma = (const float*)d_in[10];
  const float* beta  = (const float*)d_in[11];
  (void)in_sizes; (void)n_in; (void)out_size; (void)ws_size;

  char* ws = (char*)d_ws;
  u16*   bufA  = (u16*)ws;                          // 134,217,728 B : y [l][d], then pre [o][l]
  float* spart = (float*)(ws + 134217728);          //   2,097,152 B : BN partials [128][4096]
  float* sfin  = (float*)(ws + 136314880);          //         512 B : mean/rstd
  u16*   w1g   = (u16*)(ws + 136315392);            //      24,576 B : premixed conv1 weights
  float* b1g   = (float*)(ws + 136339968);          //         256 B (slot 8 KB)
  u16*   w2t   = (u16*)(ws + 136348160);            //      24,576 B
  u16*   wrt   = (u16*)(ws + 136372736);            //       8,192 B
  float* bias3 = (float*)(ws + 136380928);          //         768 B : bias(l) tables
  u16*   gbuf  = (u16*)d_out;                       // d_out [0, 128MiB): core (bf16, [l][d])
  u16*   bufR  = (u16*)d_out + 67108864;            // d_out [128MiB, 256MiB): residual (chunk-major)

  k_prep<<<16, 256, 0, stream>>>(w1, b1, gw, w2, wr, gb, b2, br, w1g, b1g, w2t, wrt, bias3);
  k_p1<<<dim3(512, 8, 1), 256, 0, stream>>>(x, w1g, b1g, wrt, w2t, bufA, bufR);
  k_p3<<<4096, 256, 0, stream>>>(bufA, adj, bias3, gbuf);
  k_p4<<<4096, 256, 0, stream>>>(gbuf, bufR, bufA, spart);
  k_p5<<<64, 256, 0, stream>>>(spart, sfin);
  k_p6<<<2048, 256, 0, stream>>>(bufA, sfin, gamma, beta, (float*)d_out);
}

// Round 19
// 538.935 us; speedup vs baseline: 1.0492x; 1.0492x over previous
//
#include <hip/hip_runtime.h>
#include <hip/hip_bf16.h>
#include <stdint.h>

// STGCN block, MI355X gfx950. B=8 N=512 C=H=O=64 L=256 K=3.
// ROUND-14 CHAMPION (540.6 us), restored verbatim.
// ALL global I/O is float32 (reference dtypes). Internal intermediates bf16.
// LAYOUTS: xw / g = [bn][l][d]; pre = [bn][o][l] (canonical);
// res = [bn][v][t] chunk-major (contiguous store AND load).
// Pipeline:
//   P0 prep:  W1G premix (conv1*gw), b1g, w2t, wrt (f32->bf16)
//   P1: res = wr@x, xw = conv(x;W1G)+b1g -> bufA [l][d]
//   P3: g[b] = adj[b] @ xw[b] + gb -> d_out 1st half [l][d]
//   P4: pre = conv2(g)+b2+br+res (canonical [o][l]) -> bufA, + BN partials
//   P5: reduce partials -> mean, rstd
//   P6: out = relu((pre-mean)*rstd*gamma+beta) -> d_out (f32)
// MFMA (m91/m97): A row=lane&15,k=(lane>>4)*8+e; B col=lane&15; D col=lane&15,row=(lane>>4)*4+reg
// Staging LDS tiles: row l = 128B of 64 bf16, byte swizzle cb ^= ((l&7)<<4).
// pre bounce: u16[o*256 + (l ^ ((o&7)*8))] (round-9-proven).

typedef unsigned short u16;
typedef unsigned int   u32;
typedef __attribute__((ext_vector_type(8))) short           bf16x8;
typedef __attribute__((ext_vector_type(8))) unsigned short  u16x8;
typedef __attribute__((ext_vector_type(4))) unsigned short  u16x4;
typedef __attribute__((ext_vector_type(4))) float           f32x4;

__device__ __forceinline__ float bf2f(u16 v){
  union { u32 u; float f; } x; x.u = ((u32)v) << 16; return x.f;
}
__device__ __forceinline__ u16 f2bf(float f){
  __hip_bfloat16 h = __float2bfloat16(f);
  return *reinterpret_cast<u16*>(&h);
}
__device__ __forceinline__ u32 swz(int row, int cbyte){
  return (u32)(row * 128) + (u32)(cbyte ^ ((row & 7) << 4));
}

// ---------------- P0: weight prep (premix conv1 with gw) ----------------
__global__ __launch_bounds__(256) void k_prep(const float* __restrict__ w1, const float* __restrict__ b1,
    const float* __restrict__ gw, const float* __restrict__ w2, const float* __restrict__ wr,
    u16* __restrict__ w1g, float* __restrict__ b1g, u16* __restrict__ w2t, u16* __restrict__ wrt){
  const int gt = blockIdx.x * 256 + threadIdx.x, gs = gridDim.x * 256;
  for (int e = gt; e < 12288; e += gs){
    int tap = e >> 12, rem = e & 4095, o = rem >> 6, c = rem & 63;
    w2t[e] = f2bf(w2[(o * 64 + c) * 3 + tap]);
    float s = 0.f;
    for (int h = 0; h < 64; ++h)
      s += gw[h * 64 + o] * w1[(h * 64 + c) * 3 + tap];   // o plays role of d
    w1g[e] = f2bf(s);
  }
  for (int e = gt; e < 4096; e += gs) wrt[e] = f2bf(wr[e]);
  for (int d = gt; d < 64; d += gs){
    float s = 0.f;
    for (int h = 0; h < 64; ++h) s += b1[h] * gw[h * 64 + d];
    b1g[d] = s;
  }
}

// ---------------- P1: res = wr@x ; xw = conv(x; W1G) + b1g ----------------
__global__ __launch_bounds__(256) void k_p1(const float* __restrict__ x,
    const u16* __restrict__ w1g, const float* __restrict__ b1g,
    const u16* __restrict__ wrt, u16* __restrict__ outA, u16* __restrict__ outR){
  __shared__ u16 tile[16384];  // x_t [l][c] (32 KB), later reused as xw bounce [l][d]
  const int t = threadIdx.x;
  const size_t bn = (size_t)blockIdx.x + (size_t)blockIdx.y * 512;
  const float* xb = x + bn * 16384;

  // coalesced transpose-stage: each f32x4 load instr covers 16 fully-consumed lines.
  {
    const int c0 = (t >> 3) * 2;           // channel pair
    #pragma unroll
    for (int v = 0; v < 8; ++v){
      const int l0 = (t & 7) * 4 + v * 32;
      f32x4 a = *(const f32x4*)(xb + (size_t)c0 * 256 + l0);
      f32x4 b = *(const f32x4*)(xb + (size_t)(c0 + 1) * 256 + l0);
      #pragma unroll
      for (int e = 0; e < 4; ++e){
        u32 p = (u32)f2bf(a[e]) | ((u32)f2bf(b[e]) << 16);
        *(u32*)((char*)tile + swz(l0 + e, c0 * 2)) = p;
      }
    }
  }
  __syncthreads();
  const int w = t >> 6, ln = t & 63, lq = ln >> 4, lr = ln & 15;
  const bf16x8 z8 = {};

  // ---- residual: racc = wr @ x  (chunk-major contiguous store) ----
  {
    f32x4 racc[4][4];
    #pragma unroll
    for (int i = 0; i < 4; ++i)
      #pragma unroll
      for (int j = 0; j < 4; ++j) racc[i][j] = (f32x4){0.f, 0.f, 0.f, 0.f};
    #pragma unroll
    for (int kk = 0; kk < 2; ++kk){
      bf16x8 A[4];
      #pragma unroll
      for (int fo = 0; fo < 4; ++fo)
        A[fo] = *(const bf16x8*)(wrt + (fo * 16 + lr) * 64 + kk * 32 + lq * 8);
      #pragma unroll
      for (int fc = 0; fc < 4; ++fc){
        int l = w * 64 + fc * 16 + lr;
        bf16x8 B = *(const bf16x8*)((char*)tile + swz(l, kk * 64 + lq * 16));
        #pragma unroll
        for (int fo = 0; fo < 4; ++fo)
          racc[fo][fc] = __builtin_amdgcn_mfma_f32_16x16x32_bf16(A[fo], B, racc[fo][fc], 0, 0, 0);
      }
    }
    #pragma unroll
    for (int v = 0; v < 8; ++v){
      u16x8 ov;
      const int fo = v >> 1;
      #pragma unroll
      for (int h = 0; h < 2; ++h){
        const int fc = (v & 1) * 2 + h;
        #pragma unroll
        for (int r2 = 0; r2 < 4; ++r2)
          ov[h * 4 + r2] = f2bf(racc[fo][fc][r2]);
      }
      *(u16x8*)(outR + bn * 16384 + v * 2048 + t * 8) = ov;  // contiguous 2KB/instr
    }
  }

  // ---- xw = conv(x; W1G), premixed weights ----
  f32x4 acc[4][4];
  #pragma unroll
  for (int i = 0; i < 4; ++i)
    #pragma unroll
    for (int j = 0; j < 4; ++j) acc[i][j] = (f32x4){0.f, 0.f, 0.f, 0.f};
  #pragma unroll
  for (int tap = 0; tap < 3; ++tap){
    #pragma unroll
    for (int kk = 0; kk < 2; ++kk){
      bf16x8 A[4];
      #pragma unroll
      for (int fo = 0; fo < 4; ++fo)
        A[fo] = *(const bf16x8*)(w1g + tap * 4096 + (fo * 16 + lr) * 64 + kk * 32 + lq * 8);
      #pragma unroll
      for (int fc = 0; fc < 4; ++fc){
        int r = w * 64 + fc * 16 + lr + tap - 1;       // conv pad=1
        int rc = r < 0 ? 0 : (r > 255 ? 255 : r);
        bf16x8 B = *(const bf16x8*)((char*)tile + swz(rc, kk * 64 + lq * 16));
        if (r != rc) B = z8;
        #pragma unroll
        for (int fo = 0; fo < 4; ++fo)
          acc[fo][fc] = __builtin_amdgcn_mfma_f32_16x16x32_bf16(A[fo], B, acc[fo][fc], 0, 0, 0);
      }
    }
  }
  __syncthreads();   // all tile reads done -> reuse tile as [l][d] bounce
  #pragma unroll
  for (int fo = 0; fo < 4; ++fo){
    float bb[4];
    #pragma unroll
    for (int r2 = 0; r2 < 4; ++r2) bb[r2] = b1g[fo * 16 + lq * 4 + r2];
    #pragma unroll
    for (int fc = 0; fc < 4; ++fc){
      int l = w * 64 + fc * 16 + lr;
      #pragma unroll
      for (int r2 = 0; r2 < 4; ++r2){
        int d = fo * 16 + lq * 4 + r2;
        *(u16*)((char*)tile + l * 128 + ((2 * d) ^ ((l & 7) << 4))) = f2bf(acc[fo][fc][r2] + bb[r2]);
      }
    }
  }
  __syncthreads();
  // vector store [l][d]: 8 x u16x8, fully-lined
  u16* op = outA + bn * 16384;
  #pragma unroll
  for (int v = 0; v < 8; ++v){
    int flat = v * 2048 + t * 8;
    int l = flat >> 6, d0 = flat & 63;
    u16x8 val = *(const u16x8*)((char*)tile + l * 128 + ((d0 * 2) ^ ((l & 7) << 4)));
    *(u16x8*)(op + flat) = val;
  }
}

// ---------------- P3: g = adj @ xw + gb  (reg-prefetch, XCD swizzle) ----------------
__global__ __launch_bounds__(256) void k_p3(const u16* __restrict__ xw,
    const float* __restrict__ adj, const float* __restrict__ gbv, u16* __restrict__ outB){
  __shared__ u16 At[8192];  // adj tile [128 n][64 m], swizzled (16 KB)
  __shared__ u16 Bt[8192];  // xw tile transposed [128 j][64 m], swizzled (16 KB)
  const int t = threadIdx.x;
  const int wg = ((blockIdx.x & 7) << 9) | ((int)blockIdx.x >> 3);
  const int jt = wg & 127, nt = (wg >> 7) & 3, b = wg >> 9;
  const float* adjb = adj + ((size_t)b * 512 + (size_t)nt * 128) * 512;
  const u16* Xb = xw + (size_t)b * 8388608 + (size_t)jt * 128;
  const int w = t >> 6, ln = t & 63, lq = ln >> 4, lr = ln & 15;
  const int wrow = w >> 1, wcol = w & 1;
  const int mpair = t & 31, jq = t >> 5;
  f32x4 acc[4][4];
  #pragma unroll
  for (int i = 0; i < 4; ++i)
    #pragma unroll
    for (int j = 0; j < 4; ++j) acc[i][j] = (f32x4){0.f, 0.f, 0.f, 0.f};

  f32x4 ra[8];
  u16x8 rb[4];
  auto LOADK = [&](int ks){
    #pragma unroll
    for (int it = 0; it < 8; ++it){
      int c = it * 256 + t;
      int row = c >> 4, mc = c & 15;
      ra[it] = *(const f32x4*)(adjb + (size_t)row * 512 + ks * 64 + mc * 4);
    }
    const u16* s0 = Xb + (size_t)(ks * 64 + mpair * 2) * 16384 + jq * 16;
    const u16* s1 = s0 + 16384;
    #pragma unroll
    for (int v2 = 0; v2 < 2; ++v2){
      rb[v2 * 2]     = *(const u16x8*)(s0 + v2 * 8);
      rb[v2 * 2 + 1] = *(const u16x8*)(s1 + v2 * 8);
    }
  };

  LOADK(0);
  for (int ks = 0; ks < 8; ++ks){
    #pragma unroll
    for (int it = 0; it < 8; ++it){
      int c = it * 256 + t;
      int row = c >> 4, mc = c & 15;
      u16x4 pk;
      #pragma unroll
      for (int e = 0; e < 4; ++e) pk[e] = f2bf(ra[it][e]);
      *(u16x4*)((char*)At + (u32)(row * 128) + (u32)((mc * 8) ^ ((row & 7) << 4))) = pk;
    }
    #pragma unroll
    for (int v2 = 0; v2 < 2; ++v2){
      #pragma unroll
      for (int e = 0; e < 8; ++e){
        u32 p = (u32)(u16)rb[v2 * 2][e] | ((u32)(u16)rb[v2 * 2 + 1][e] << 16);
        *(u32*)((char*)Bt + swz(jq * 16 + v2 * 8 + e, mpair * 4)) = p;
      }
    }
    __syncthreads();
    if (ks < 7) LOADK(ks + 1);   // next-tile loads in flight during compute
    #pragma unroll
    for (int kk = 0; kk < 2; ++kk){
      bf16x8 Af[4], Bf[4];
      #pragma unroll
      for (int f = 0; f < 4; ++f){
        int rA = wrow * 64 + f * 16 + lr;
        Af[f] = *(const bf16x8*)((char*)At + swz(rA, kk * 64 + lq * 16));
        int rB = wcol * 64 + f * 16 + lr;
        Bf[f] = *(const bf16x8*)((char*)Bt + swz(rB, kk * 64 + lq * 16));
      }
      #pragma unroll
      for (int fr = 0; fr < 4; ++fr)
        #pragma unroll
        for (int fc = 0; fc < 4; ++fc)
          acc[fr][fc] = __builtin_amdgcn_mfma_f32_16x16x32_bf16(Af[fr], Bf[fc], acc[fr][fc], 0, 0, 0);
    }
    __syncthreads();
  }
  // j = l*64+d -> bias d = (fc*16+lr), per-lane
  float gbl[4];
  #pragma unroll
  for (int fc = 0; fc < 4; ++fc) gbl[fc] = gbv[fc * 16 + lr];
  u16* ob = outB + ((size_t)b * 512 + (size_t)nt * 128) * 16384 + (size_t)jt * 128;
  #pragma unroll
  for (int fr = 0; fr < 4; ++fr)
    #pragma unroll
    for (int fc = 0; fc < 4; ++fc)
      #pragma unroll
      for (int r2 = 0; r2 < 4; ++r2){
        int n_ = wrow * 64 + fr * 16 + lq * 4 + r2;
        int j_ = wcol * 64 + fc * 16 + lr;
        ob[(size_t)n_ * 16384 + j_] = f2bf(acc[fr][fc][r2] + gbl[fc]);
      }
}

// ---------------- P4: pre = conv2(g)+b2+br+res ; BN partials ----------------
__global__ __launch_bounds__(256) void k_p4(const u16* __restrict__ g,
    const u16* __restrict__ resv, const u16* __restrict__ w2t,
    const float* __restrict__ b2v, const float* __restrict__ brv,
    u16* __restrict__ outP, float* __restrict__ spart){
  __shared__ u16 gt2[16384];  // g tile [l][d] (straight swizzled copy), then pre bounce [o][l]
  __shared__ float sc2[512];  // BN scratch (2 KB)
  const int t = threadIdx.x;
  const size_t bn = (size_t)blockIdx.x + (size_t)blockIdx.y * 512;
  const u16* gb = g + bn * 16384;
  // straight copy: coalesced u16x8 loads + conflict-free 16B swizzled LDS writes
  #pragma unroll
  for (int v = 0; v < 8; ++v){
    int flat = v * 2048 + t * 8;
    int l = flat >> 6, d0 = flat & 63;
    u16x8 val = *(const u16x8*)(gb + flat);
    *(u16x8*)((char*)gt2 + l * 128 + ((d0 * 2) ^ ((l & 7) << 4))) = val;
  }
  __syncthreads();
  const int w = t >> 6, ln = t & 63, lq = ln >> 4, lr = ln & 15;
  const bf16x8 z8 = {};

  // res loads issued early (chunk-major contiguous; in flight under the MFMAs)
  u16x8 rv[8];
  #pragma unroll
  for (int v = 0; v < 8; ++v) rv[v] = *(const u16x8*)(resv + bn * 16384 + v * 2048 + t * 8);

  f32x4 acc[4][4];
  #pragma unroll
  for (int i = 0; i < 4; ++i)
    #pragma unroll
    for (int j = 0; j < 4; ++j) acc[i][j] = (f32x4){0.f, 0.f, 0.f, 0.f};

  #pragma unroll
  for (int tap = 0; tap < 3; ++tap){
    #pragma unroll
    for (int kk = 0; kk < 2; ++kk){
      bf16x8 A[4];
      #pragma unroll
      for (int fo = 0; fo < 4; ++fo)
        A[fo] = *(const bf16x8*)(w2t + tap * 4096 + (fo * 16 + lr) * 64 + kk * 32 + lq * 8);
      #pragma unroll
      for (int fc = 0; fc < 4; ++fc){
        int r = w * 64 + fc * 16 + lr + tap - 1;
        int rc = r < 0 ? 0 : (r > 255 ? 255 : r);
        bf16x8 B = *(const bf16x8*)((char*)gt2 + swz(rc, kk * 64 + lq * 16));
        if (r != rc) B = z8;
        #pragma unroll
        for (int fo = 0; fo < 4; ++fo)
          acc[fo][fc] = __builtin_amdgcn_mfma_f32_16x16x32_bf16(A[fo], B, acc[fo][fc], 0, 0, 0);
      }
    }
  }
  __syncthreads();   // all gt2 reads done -> reuse as pre bounce [o][l]

  float psum[16], psq[16];
  #pragma unroll
  for (int i = 0; i < 16; ++i){ psum[i] = 0.f; psq[i] = 0.f; }
  #pragma unroll
  for (int fo = 0; fo < 4; ++fo){
    float bb[4];
    #pragma unroll
    for (int r2 = 0; r2 < 4; ++r2){
      int o = fo * 16 + lq * 4 + r2;
      bb[r2] = b2v[o] + brv[o];
    }
    #pragma unroll
    for (int fc = 0; fc < 4; ++fc){
      int l = w * 64 + fc * 16 + lr;
      #pragma unroll
      for (int r2 = 0; r2 < 4; ++r2){
        float val = acc[fo][fc][r2] + bb[r2]
                  + bf2f(rv[fo * 2 + (fc >> 1)][(fc & 1) * 4 + r2]);
        int o = fo * 16 + lq * 4 + r2;
        gt2[o * 256 + (l ^ ((o & 7) * 8))] = f2bf(val);   // [o][l] bounce (round-9-proven)
        psum[fo * 4 + r2] += val;
        psq[fo * 4 + r2] += val * val;
      }
    }
  }
  // reduce over the 16 lr lanes, deterministic
  #pragma unroll
  for (int i = 0; i < 16; ++i){
    #pragma unroll
    for (int m = 1; m < 16; m <<= 1){
      psum[i] += __shfl_xor(psum[i], m, 64);
      psq[i]  += __shfl_xor(psq[i],  m, 64);
    }
  }
  if (lr == 0){
    #pragma unroll
    for (int i = 0; i < 16; ++i){
      int o = (i >> 2) * 16 + lq * 4 + (i & 3);
      sc2[w * 128 + o]      = psum[i];
      sc2[w * 128 + 64 + o] = psq[i];
    }
  }
  __syncthreads();
  // vectorized canonical pre store [o][l] (round-9-proven)
  u16* op = outP + bn * 16384;
  #pragma unroll
  for (int v = 0; v < 8; ++v){
    int d = (t >> 5) + v * 8;
    int l0 = (t & 31) * 8;
    u16x8 val = *(const u16x8*)(gt2 + d * 256 + (l0 ^ ((d & 7) * 8)));
    *(u16x8*)(op + v * 2048 + t * 8) = val;
  }
  if (t < 128){
    float tot = sc2[t] + sc2[128 + t] + sc2[256 + t] + sc2[384 + t];
    spart[(size_t)t * 4096 + bn] = tot;   // [0..63]=sum(o), [64..127]=sumsq(o)
  }
}

// ---------------- P5: BN stats finalize ----------------
__global__ __launch_bounds__(256) void k_p5(const float* __restrict__ part, float* __restrict__ fin){
  const int o = blockIdx.x, t = threadIdx.x;
  float s1 = 0.f, s2 = 0.f;
  for (int k = t; k < 4096; k += 256){
    s1 += part[(size_t)o * 4096 + k];
    s2 += part[(size_t)(64 + o) * 4096 + k];
  }
  #pragma unroll
  for (int m = 32; m; m >>= 1){
    s1 += __shfl_down(s1, m, 64);
    s2 += __shfl_down(s2, m, 64);
  }
  __shared__ float red[8];
  if ((t & 63) == 0){ red[(t >> 6) * 2] = s1; red[(t >> 6) * 2 + 1] = s2; }
  __syncthreads();
  if (t == 0){
    float S1 = red[0] + red[2] + red[4] + red[6];
    float S2 = red[1] + red[3] + red[5] + red[7];
    const float invN = 1.f / 1048576.f;
    float mean = S1 * invN;
    float var = S2 * invN - mean * mean;
    fin[o] = mean;
    fin[64 + o] = rsqrtf(var + 1e-5f);
  }
}

// ---------------- P6: normalize + affine + relu (canonical [o][l] pre -> f32 out) ----------------
__global__ __launch_bounds__(256) void k_p6(const u16* __restrict__ pre, const float* __restrict__ fin,
    const float* __restrict__ gamma, const float* __restrict__ beta, float* __restrict__ out){
  __shared__ float ssca[64], soff[64];
  const int tt = threadIdx.x;
  if (tt < 64){
    float sc = fin[64 + tt] * gamma[tt];
    ssca[tt] = sc;
    soff[tt] = beta[tt] - fin[tt] * sc;
  }
  __syncthreads();
  const size_t nchunk = 8388608;  // 67108864 / 8
  for (size_t i = (size_t)blockIdx.x * 256 + tt; i < nchunk; i += (size_t)gridDim.x * 256){
    int o = (int)((i >> 5) & 63);   // canonical: within-bn flat = o*256+l, 8 elems share o
    float sca = ssca[o], off = soff[o];
    u16x8 v = *(const u16x8*)(pre + i * 8);
    f32x4 oa, ob;
    #pragma unroll
    for (int e = 0; e < 4; ++e){
      float f0 = bf2f(v[e]) * sca + off;
      float f1 = bf2f(v[4 + e]) * sca + off;
      oa[e] = f0 > 0.f ? f0 : 0.f;
      ob[e] = f1 > 0.f ? f1 : 0.f;
    }
    *(f32x4*)(out + i * 8)     = oa;
    *(f32x4*)(out + i * 8 + 4) = ob;
  }
}

extern "C" void kernel_launch(void* const* d_in, const int* in_sizes, int n_in,
                              void* d_out, int out_size, void* d_ws, size_t ws_size,
                              hipStream_t stream){
  const float* x     = (const float*)d_in[0];
  const float* adj   = (const float*)d_in[1];
  const float* w1    = (const float*)d_in[2];
  const float* b1    = (const float*)d_in[3];
  const float* gw    = (const float*)d_in[4];
  const float* gb    = (const float*)d_in[5];
  const float* w2    = (const float*)d_in[6];
  const float* b2    = (const float*)d_in[7];
  const float* wr    = (const float*)d_in[8];
  const float* br    = (const float*)d_in[9];
  const float* gamma = (const float*)d_in[10];
  const float* beta  = (const float*)d_in[11];
  (void)in_sizes; (void)n_in; (void)out_size; (void)ws_size;

  char* ws = (char*)d_ws;
  u16*   bufA  = (u16*)ws;                          // 134,217,728 B : xw [l][d], then pre [o][l]
  float* spart = (float*)(ws + 134217728);          //   2,097,152 B : BN partials [128][4096]
  float* sfin  = (float*)(ws + 136314880);          //         512 B : mean/rstd
  u16*   w1g   = (u16*)(ws + 136315392);            //      24,576 B : premixed conv1 weights
  float* b1g   = (float*)(ws + 136339968);          //         256 B (slot 8 KB)
  u16*   w2t   = (u16*)(ws + 136348160);            //      24,576 B
  u16*   wrt   = (u16*)(ws + 136372736);            //       8,192 B
  u16*   gbuf  = (u16*)d_out;                       // d_out [0, 128MiB): g scratch (bf16, [l][d])
  u16*   bufR  = (u16*)d_out + 67108864;            // d_out [128MiB, 256MiB): residual (chunk-major)

  k_prep<<<16, 256, 0, stream>>>(w1, b1, gw, w2, wr, w1g, b1g, w2t, wrt);
  k_p1<<<dim3(512, 8, 1), 256, 0, stream>>>(x, w1g, b1g, wrt, bufA, bufR);
  k_p3<<<4096, 256, 0, stream>>>(bufA, adj, gb, gbuf);
  k_p4<<<dim3(512, 8, 1), 256, 0, stream>>>(gbuf, bufR, w2t, b2, br, bufA, spart);
  k_p5<<<64, 256, 0, stream>>>(spart, sfin);
  k_p6<<<2048, 256, 0, stream>>>(bufA, sfin, gamma, beta, (float*)d_out);
}

// Round 20
// 537.816 us; speedup vs baseline: 1.0514x; 1.0021x over previous
//
#include <hip/hip_runtime.h>
#include <hip/hip_bf16.h>
#include <stdint.h>

// STGCN block, MI355X gfx950. B=8 N=512 C=H=O=64 L=256 K=3.
// SESSION CHAMPION (538.9 us, round 19) — resubmitted verbatim.
// ALL global I/O is float32 (reference dtypes). Internal intermediates bf16.
// LAYOUTS: xw / g = [bn][l][d]; pre = [bn][o][l] (canonical);
// res = [bn][v][t] chunk-major (contiguous store AND load).
// Pipeline:
//   P0 prep:  W1G premix (conv1*gw), b1g, w2t, wrt (f32->bf16)
//   P1: res = wr@x, xw = conv(x;W1G)+b1g -> bufA [l][d]
//   P3: g[b] = adj[b] @ xw[b] + gb -> d_out 1st half [l][d]
//   P4: pre = conv2(g)+b2+br+res (canonical [o][l]) -> bufA, + BN partials
//   P5: reduce partials -> mean, rstd
//   P6: out = relu((pre-mean)*rstd*gamma+beta) -> d_out (f32)
// MFMA (m91/m97): A row=lane&15,k=(lane>>4)*8+e; B col=lane&15; D col=lane&15,row=(lane>>4)*4+reg
// Staging LDS tiles: row l = 128B of 64 bf16, byte swizzle cb ^= ((l&7)<<4).
// pre bounce: u16[o*256 + (l ^ ((o&7)*8))].

typedef unsigned short u16;
typedef unsigned int   u32;
typedef __attribute__((ext_vector_type(8))) short           bf16x8;
typedef __attribute__((ext_vector_type(8))) unsigned short  u16x8;
typedef __attribute__((ext_vector_type(4))) unsigned short  u16x4;
typedef __attribute__((ext_vector_type(4))) float           f32x4;

__device__ __forceinline__ float bf2f(u16 v){
  union { u32 u; float f; } x; x.u = ((u32)v) << 16; return x.f;
}
__device__ __forceinline__ u16 f2bf(float f){
  __hip_bfloat16 h = __float2bfloat16(f);
  return *reinterpret_cast<u16*>(&h);
}
__device__ __forceinline__ u32 swz(int row, int cbyte){
  return (u32)(row * 128) + (u32)(cbyte ^ ((row & 7) << 4));
}

// ---------------- P0: weight prep (premix conv1 with gw) ----------------
__global__ __launch_bounds__(256) void k_prep(const float* __restrict__ w1, const float* __restrict__ b1,
    const float* __restrict__ gw, const float* __restrict__ w2, const float* __restrict__ wr,
    u16* __restrict__ w1g, float* __restrict__ b1g, u16* __restrict__ w2t, u16* __restrict__ wrt){
  const int gt = blockIdx.x * 256 + threadIdx.x, gs = gridDim.x * 256;
  for (int e = gt; e < 12288; e += gs){
    int tap = e >> 12, rem = e & 4095, o = rem >> 6, c = rem & 63;
    w2t[e] = f2bf(w2[(o * 64 + c) * 3 + tap]);
    float s = 0.f;
    for (int h = 0; h < 64; ++h)
      s += gw[h * 64 + o] * w1[(h * 64 + c) * 3 + tap];   // o plays role of d
    w1g[e] = f2bf(s);
  }
  for (int e = gt; e < 4096; e += gs) wrt[e] = f2bf(wr[e]);
  for (int d = gt; d < 64; d += gs){
    float s = 0.f;
    for (int h = 0; h < 64; ++h) s += b1[h] * gw[h * 64 + d];
    b1g[d] = s;
  }
}

// ---------------- P1: res = wr@x ; xw = conv(x; W1G) + b1g ----------------
__global__ __launch_bounds__(256) void k_p1(const float* __restrict__ x,
    const u16* __restrict__ w1g, const float* __restrict__ b1g,
    const u16* __restrict__ wrt, u16* __restrict__ outA, u16* __restrict__ outR){
  __shared__ u16 tile[16384];  // x_t [l][c] (32 KB), later reused as xw bounce [l][d]
  const int t = threadIdx.x;
  const size_t bn = (size_t)blockIdx.x + (size_t)blockIdx.y * 512;
  const float* xb = x + bn * 16384;

  // coalesced transpose-stage: each f32x4 load instr covers 16 fully-consumed lines.
  {
    const int c0 = (t >> 3) * 2;           // channel pair
    #pragma unroll
    for (int v = 0; v < 8; ++v){
      const int l0 = (t & 7) * 4 + v * 32;
      f32x4 a = *(const f32x4*)(xb + (size_t)c0 * 256 + l0);
      f32x4 b = *(const f32x4*)(xb + (size_t)(c0 + 1) * 256 + l0);
      #pragma unroll
      for (int e = 0; e < 4; ++e){
        u32 p = (u32)f2bf(a[e]) | ((u32)f2bf(b[e]) << 16);
        *(u32*)((char*)tile + swz(l0 + e, c0 * 2)) = p;
      }
    }
  }
  __syncthreads();
  const int w = t >> 6, ln = t & 63, lq = ln >> 4, lr = ln & 15;
  const bf16x8 z8 = {};

  // ---- residual: racc = wr @ x  (chunk-major contiguous store) ----
  {
    f32x4 racc[4][4];
    #pragma unroll
    for (int i = 0; i < 4; ++i)
      #pragma unroll
      for (int j = 0; j < 4; ++j) racc[i][j] = (f32x4){0.f, 0.f, 0.f, 0.f};
    #pragma unroll
    for (int kk = 0; kk < 2; ++kk){
      bf16x8 A[4];
      #pragma unroll
      for (int fo = 0; fo < 4; ++fo)
        A[fo] = *(const bf16x8*)(wrt + (fo * 16 + lr) * 64 + kk * 32 + lq * 8);
      #pragma unroll
      for (int fc = 0; fc < 4; ++fc){
        int l = w * 64 + fc * 16 + lr;
        bf16x8 B = *(const bf16x8*)((char*)tile + swz(l, kk * 64 + lq * 16));
        #pragma unroll
        for (int fo = 0; fo < 4; ++fo)
          racc[fo][fc] = __builtin_amdgcn_mfma_f32_16x16x32_bf16(A[fo], B, racc[fo][fc], 0, 0, 0);
      }
    }
    #pragma unroll
    for (int v = 0; v < 8; ++v){
      u16x8 ov;
      const int fo = v >> 1;
      #pragma unroll
      for (int h = 0; h < 2; ++h){
        const int fc = (v & 1) * 2 + h;
        #pragma unroll
        for (int r2 = 0; r2 < 4; ++r2)
          ov[h * 4 + r2] = f2bf(racc[fo][fc][r2]);
      }
      *(u16x8*)(outR + bn * 16384 + v * 2048 + t * 8) = ov;  // contiguous 2KB/instr
    }
  }

  // ---- xw = conv(x; W1G), premixed weights ----
  f32x4 acc[4][4];
  #pragma unroll
  for (int i = 0; i < 4; ++i)
    #pragma unroll
    for (int j = 0; j < 4; ++j) acc[i][j] = (f32x4){0.f, 0.f, 0.f, 0.f};
  #pragma unroll
  for (int tap = 0; tap < 3; ++tap){
    #pragma unroll
    for (int kk = 0; kk < 2; ++kk){
      bf16x8 A[4];
      #pragma unroll
      for (int fo = 0; fo < 4; ++fo)
        A[fo] = *(const bf16x8*)(w1g + tap * 4096 + (fo * 16 + lr) * 64 + kk * 32 + lq * 8);
      #pragma unroll
      for (int fc = 0; fc < 4; ++fc){
        int r = w * 64 + fc * 16 + lr + tap - 1;       // conv pad=1
        int rc = r < 0 ? 0 : (r > 255 ? 255 : r);
        bf16x8 B = *(const bf16x8*)((char*)tile + swz(rc, kk * 64 + lq * 16));
        if (r != rc) B = z8;
        #pragma unroll
        for (int fo = 0; fo < 4; ++fo)
          acc[fo][fc] = __builtin_amdgcn_mfma_f32_16x16x32_bf16(A[fo], B, acc[fo][fc], 0, 0, 0);
      }
    }
  }
  __syncthreads();   // all tile reads done -> reuse tile as [l][d] bounce
  #pragma unroll
  for (int fo = 0; fo < 4; ++fo){
    float bb[4];
    #pragma unroll
    for (int r2 = 0; r2 < 4; ++r2) bb[r2] = b1g[fo * 16 + lq * 4 + r2];
    #pragma unroll
    for (int fc = 0; fc < 4; ++fc){
      int l = w * 64 + fc * 16 + lr;
      #pragma unroll
      for (int r2 = 0; r2 < 4; ++r2){
        int d = fo * 16 + lq * 4 + r2;
        *(u16*)((char*)tile + l * 128 + ((2 * d) ^ ((l & 7) << 4))) = f2bf(acc[fo][fc][r2] + bb[r2]);
      }
    }
  }
  __syncthreads();
  // vector store [l][d]: 8 x u16x8, fully-lined
  u16* op = outA + bn * 16384;
  #pragma unroll
  for (int v = 0; v < 8; ++v){
    int flat = v * 2048 + t * 8;
    int l = flat >> 6, d0 = flat & 63;
    u16x8 val = *(const u16x8*)((char*)tile + l * 128 + ((d0 * 2) ^ ((l & 7) << 4)));
    *(u16x8*)(op + flat) = val;
  }
}

// ---------------- P3: g = adj @ xw + gb  (reg-prefetch, XCD swizzle) ----------------
__global__ __launch_bounds__(256) void k_p3(const u16* __restrict__ xw,
    const float* __restrict__ adj, const float* __restrict__ gbv, u16* __restrict__ outB){
  __shared__ u16 At[8192];  // adj tile [128 n][64 m], swizzled (16 KB)
  __shared__ u16 Bt[8192];  // xw tile transposed [128 j][64 m], swizzled (16 KB)
  const int t = threadIdx.x;
  const int wg = ((blockIdx.x & 7) << 9) | ((int)blockIdx.x >> 3);
  const int jt = wg & 127, nt = (wg >> 7) & 3, b = wg >> 9;
  const float* adjb = adj + ((size_t)b * 512 + (size_t)nt * 128) * 512;
  const u16* Xb = xw + (size_t)b * 8388608 + (size_t)jt * 128;
  const int w = t >> 6, ln = t & 63, lq = ln >> 4, lr = ln & 15;
  const int wrow = w >> 1, wcol = w & 1;
  const int mpair = t & 31, jq = t >> 5;
  f32x4 acc[4][4];
  #pragma unroll
  for (int i = 0; i < 4; ++i)
    #pragma unroll
    for (int j = 0; j < 4; ++j) acc[i][j] = (f32x4){0.f, 0.f, 0.f, 0.f};

  f32x4 ra[8];
  u16x8 rb[4];
  auto LOADK = [&](int ks){
    #pragma unroll
    for (int it = 0; it < 8; ++it){
      int c = it * 256 + t;
      int row = c >> 4, mc = c & 15;
      ra[it] = *(const f32x4*)(adjb + (size_t)row * 512 + ks * 64 + mc * 4);
    }
    const u16* s0 = Xb + (size_t)(ks * 64 + mpair * 2) * 16384 + jq * 16;
    const u16* s1 = s0 + 16384;
    #pragma unroll
    for (int v2 = 0; v2 < 2; ++v2){
      rb[v2 * 2]     = *(const u16x8*)(s0 + v2 * 8);
      rb[v2 * 2 + 1] = *(const u16x8*)(s1 + v2 * 8);
    }
  };

  LOADK(0);
  for (int ks = 0; ks < 8; ++ks){
    #pragma unroll
    for (int it = 0; it < 8; ++it){
      int c = it * 256 + t;
      int row = c >> 4, mc = c & 15;
      u16x4 pk;
      #pragma unroll
      for (int e = 0; e < 4; ++e) pk[e] = f2bf(ra[it][e]);
      *(u16x4*)((char*)At + (u32)(row * 128) + (u32)((mc * 8) ^ ((row & 7) << 4))) = pk;
    }
    #pragma unroll
    for (int v2 = 0; v2 < 2; ++v2){
      #pragma unroll
      for (int e = 0; e < 8; ++e){
        u32 p = (u32)(u16)rb[v2 * 2][e] | ((u32)(u16)rb[v2 * 2 + 1][e] << 16);
        *(u32*)((char*)Bt + swz(jq * 16 + v2 * 8 + e, mpair * 4)) = p;
      }
    }
    __syncthreads();
    if (ks < 7) LOADK(ks + 1);   // next-tile loads in flight during compute
    #pragma unroll
    for (int kk = 0; kk < 2; ++kk){
      bf16x8 Af[4], Bf[4];
      #pragma unroll
      for (int f = 0; f < 4; ++f){
        int rA = wrow * 64 + f * 16 + lr;
        Af[f] = *(const bf16x8*)((char*)At + swz(rA, kk * 64 + lq * 16));
        int rB = wcol * 64 + f * 16 + lr;
        Bf[f] = *(const bf16x8*)((char*)Bt + swz(rB, kk * 64 + lq * 16));
      }
      #pragma unroll
      for (int fr = 0; fr < 4; ++fr)
        #pragma unroll
        for (int fc = 0; fc < 4; ++fc)
          acc[fr][fc] = __builtin_amdgcn_mfma_f32_16x16x32_bf16(Af[fr], Bf[fc], acc[fr][fc], 0, 0, 0);
    }
    __syncthreads();
  }
  // j = l*64+d -> bias d = (fc*16+lr), per-lane
  float gbl[4];
  #pragma unroll
  for (int fc = 0; fc < 4; ++fc) gbl[fc] = gbv[fc * 16 + lr];
  u16* ob = outB + ((size_t)b * 512 + (size_t)nt * 128) * 16384 + (size_t)jt * 128;
  #pragma unroll
  for (int fr = 0; fr < 4; ++fr)
    #pragma unroll
    for (int fc = 0; fc < 4; ++fc)
      #pragma unroll
      for (int r2 = 0; r2 < 4; ++r2){
        int n_ = wrow * 64 + fr * 16 + lq * 4 + r2;
        int j_ = wcol * 64 + fc * 16 + lr;
        ob[(size_t)n_ * 16384 + j_] = f2bf(acc[fr][fc][r2] + gbl[fc]);
      }
}

// ---------------- P4: pre = conv2(g)+b2+br+res ; BN partials ----------------
__global__ __launch_bounds__(256) void k_p4(const u16* __restrict__ g,
    const u16* __restrict__ resv, const u16* __restrict__ w2t,
    const float* __restrict__ b2v, const float* __restrict__ brv,
    u16* __restrict__ outP, float* __restrict__ spart){
  __shared__ u16 gt2[16384];  // g tile [l][d] (straight swizzled copy), then pre bounce [o][l]
  __shared__ float sc2[512];  // BN scratch (2 KB)
  const int t = threadIdx.x;
  const size_t bn = (size_t)blockIdx.x + (size_t)blockIdx.y * 512;
  const u16* gb = g + bn * 16384;
  // straight copy: coalesced u16x8 loads + conflict-free 16B swizzled LDS writes
  #pragma unroll
  for (int v = 0; v < 8; ++v){
    int flat = v * 2048 + t * 8;
    int l = flat >> 6, d0 = flat & 63;
    u16x8 val = *(const u16x8*)(gb + flat);
    *(u16x8*)((char*)gt2 + l * 128 + ((d0 * 2) ^ ((l & 7) << 4))) = val;
  }
  __syncthreads();
  const int w = t >> 6, ln = t & 63, lq = ln >> 4, lr = ln & 15;
  const bf16x8 z8 = {};

  // res loads issued early (chunk-major contiguous; in flight under the MFMAs)
  u16x8 rv[8];
  #pragma unroll
  for (int v = 0; v < 8; ++v) rv[v] = *(const u16x8*)(resv + bn * 16384 + v * 2048 + t * 8);

  f32x4 acc[4][4];
  #pragma unroll
  for (int i = 0; i < 4; ++i)
    #pragma unroll
    for (int j = 0; j < 4; ++j) acc[i][j] = (f32x4){0.f, 0.f, 0.f, 0.f};

  #pragma unroll
  for (int tap = 0; tap < 3; ++tap){
    #pragma unroll
    for (int kk = 0; kk < 2; ++kk){
      bf16x8 A[4];
      #pragma unroll
      for (int fo = 0; fo < 4; ++fo)
        A[fo] = *(const bf16x8*)(w2t + tap * 4096 + (fo * 16 + lr) * 64 + kk * 32 + lq * 8);
      #pragma unroll
      for (int fc = 0; fc < 4; ++fc){
        int r = w * 64 + fc * 16 + lr + tap - 1;
        int rc = r < 0 ? 0 : (r > 255 ? 255 : r);
        bf16x8 B = *(const bf16x8*)((char*)gt2 + swz(rc, kk * 64 + lq * 16));
        if (r != rc) B = z8;
        #pragma unroll
        for (int fo = 0; fo < 4; ++fo)
          acc[fo][fc] = __builtin_amdgcn_mfma_f32_16x16x32_bf16(A[fo], B, acc[fo][fc], 0, 0, 0);
      }
    }
  }
  __syncthreads();   // all gt2 reads done -> reuse as pre bounce [o][l]

  float psum[16], psq[16];
  #pragma unroll
  for (int i = 0; i < 16; ++i){ psum[i] = 0.f; psq[i] = 0.f; }
  #pragma unroll
  for (int fo = 0; fo < 4; ++fo){
    float bb[4];
    #pragma unroll
    for (int r2 = 0; r2 < 4; ++r2){
      int o = fo * 16 + lq * 4 + r2;
      bb[r2] = b2v[o] + brv[o];
    }
    #pragma unroll
    for (int fc = 0; fc < 4; ++fc){
      int l = w * 64 + fc * 16 + lr;
      #pragma unroll
      for (int r2 = 0; r2 < 4; ++r2){
        float val = acc[fo][fc][r2] + bb[r2]
                  + bf2f(rv[fo * 2 + (fc >> 1)][(fc & 1) * 4 + r2]);
        int o = fo * 16 + lq * 4 + r2;
        gt2[o * 256 + (l ^ ((o & 7) * 8))] = f2bf(val);   // [o][l] bounce
        psum[fo * 4 + r2] += val;
        psq[fo * 4 + r2] += val * val;
      }
    }
  }
  // reduce over the 16 lr lanes, deterministic
  #pragma unroll
  for (int i = 0; i < 16; ++i){
    #pragma unroll
    for (int m = 1; m < 16; m <<= 1){
      psum[i] += __shfl_xor(psum[i], m, 64);
      psq[i]  += __shfl_xor(psq[i],  m, 64);
    }
  }
  if (lr == 0){
    #pragma unroll
    for (int i = 0; i < 16; ++i){
      int o = (i >> 2) * 16 + lq * 4 + (i & 3);
      sc2[w * 128 + o]      = psum[i];
      sc2[w * 128 + 64 + o] = psq[i];
    }
  }
  __syncthreads();
  // vectorized canonical pre store [o][l]
  u16* op = outP + bn * 16384;
  #pragma unroll
  for (int v = 0; v < 8; ++v){
    int d = (t >> 5) + v * 8;
    int l0 = (t & 31) * 8;
    u16x8 val = *(const u16x8*)(gt2 + d * 256 + (l0 ^ ((d & 7) * 8)));
    *(u16x8*)(op + v * 2048 + t * 8) = val;
  }
  if (t < 128){
    float tot = sc2[t] + sc2[128 + t] + sc2[256 + t] + sc2[384 + t];
    spart[(size_t)t * 4096 + bn] = tot;   // [0..63]=sum(o), [64..127]=sumsq(o)
  }
}

// ---------------- P5: BN stats finalize ----------------
__global__ __launch_bounds__(256) void k_p5(const float* __restrict__ part, float* __restrict__ fin){
  const int o = blockIdx.x, t = threadIdx.x;
  float s1 = 0.f, s2 = 0.f;
  for (int k = t; k < 4096; k += 256){
    s1 += part[(size_t)o * 4096 + k];
    s2 += part[(size_t)(64 + o) * 4096 + k];
  }
  #pragma unroll
  for (int m = 32; m; m >>= 1){
    s1 += __shfl_down(s1, m, 64);
    s2 += __shfl_down(s2, m, 64);
  }
  __shared__ float red[8];
  if ((t & 63) == 0){ red[(t >> 6) * 2] = s1; red[(t >> 6) * 2 + 1] = s2; }
  __syncthreads();
  if (t == 0){
    float S1 = red[0] + red[2] + red[4] + red[6];
    float S2 = red[1] + red[3] + red[5] + red[7];
    const float invN = 1.f / 1048576.f;
    float mean = S1 * invN;
    float var = S2 * invN - mean * mean;
    fin[o] = mean;
    fin[64 + o] = rsqrtf(var + 1e-5f);
  }
}

// ---------------- P6: normalize + affine + relu (canonical [o][l] pre -> f32 out) ----------------
__global__ __launch_bounds__(256) void k_p6(const u16* __restrict__ pre, const float* __restrict__ fin,
    const float* __restrict__ gamma, const float* __restrict__ beta, float* __restrict__ out){
  __shared__ float ssca[64], soff[64];
  const int tt = threadIdx.x;
  if (tt < 64){
    float sc = fin[64 + tt] * gamma[tt];
    ssca[tt] = sc;
    soff[tt] = beta[tt] - fin[tt] * sc;
  }
  __syncthreads();
  const size_t nchunk = 8388608;  // 67108864 / 8
  for (size_t i = (size_t)blockIdx.x * 256 + tt; i < nchunk; i += (size_t)gridDim.x * 256){
    int o = (int)((i >> 5) & 63);   // canonical: within-bn flat = o*256+l, 8 elems share o
    float sca = ssca[o], off = soff[o];
    u16x8 v = *(const u16x8*)(pre + i * 8);
    f32x4 oa, ob;
    #pragma unroll
    for (int e = 0; e < 4; ++e){
      float f0 = bf2f(v[e]) * sca + off;
      float f1 = bf2f(v[4 + e]) * sca + off;
      oa[e] = f0 > 0.f ? f0 : 0.f;
      ob[e] = f1 > 0.f ? f1 : 0.f;
    }
    *(f32x4*)(out + i * 8)     = oa;
    *(f32x4*)(out + i * 8 + 4) = ob;
  }
}

extern "C" void kernel_launch(void* const* d_in, const int* in_sizes, int n_in,
                              void* d_out, int out_size, void* d_ws, size_t ws_size,
                              hipStream_t stream){
  const float* x     = (const float*)d_in[0];
  const float* adj   = (const float*)d_in[1];
  const float* w1    = (const float*)d_in[2];
  const float* b1    = (const float*)d_in[3];
  const float* gw    = (const float*)d_in[4];
  const float* gb    = (const float*)d_in[5];
  const float* w2    = (const float*)d_in[6];
  const float* b2    = (const float*)d_in[7];
  const float* wr    = (const float*)d_in[8];
  const float* br    = (const float*)d_in[9];
  const float* gamma = (const float*)d_in[10];
  const float* beta  = (const float*)d_in[11];
  (void)in_sizes; (void)n_in; (void)out_size; (void)ws_size;

  char* ws = (char*)d_ws;
  u16*   bufA  = (u16*)ws;                          // 134,217,728 B : xw [l][d], then pre [o][l]
  float* spart = (float*)(ws + 134217728);          //   2,097,152 B : BN partials [128][4096]
  float* sfin  = (float*)(ws + 136314880);          //         512 B : mean/rstd
  u16*   w1g   = (u16*)(ws + 136315392);            //      24,576 B : premixed conv1 weights
  float* b1g   = (float*)(ws + 136339968);          //         256 B (slot 8 KB)
  u16*   w2t   = (u16*)(ws + 136348160);            //      24,576 B
  u16*   wrt   = (u16*)(ws + 136372736);            //       8,192 B
  u16*   gbuf  = (u16*)d_out;                       // d_out [0, 128MiB): g scratch (bf16, [l][d])
  u16*   bufR  = (u16*)d_out + 67108864;            // d_out [128MiB, 256MiB): residual (chunk-major)

  k_prep<<<16, 256, 0, stream>>>(w1, b1, gw, w2, wr, w1g, b1g, w2t, wrt);
  k_p1<<<dim3(512, 8, 1), 256, 0, stream>>>(x, w1g, b1g, wrt, bufA, bufR);
  k_p3<<<4096, 256, 0, stream>>>(bufA, adj, gb, gbuf);
  k_p4<<<dim3(512, 8, 1), 256, 0, stream>>>(gbuf, bufR, w2t, b2, br, bufA, spart);
  k_p5<<<64, 256, 0, stream>>>(spart, sfin);
  k_p6<<<2048, 256, 0, stream>>>(bufA, sfin, gamma, beta, (float*)d_out);
}